// Round 1
// baseline (110.541 us; speedup 1.0000x reference)
//
#include <hip/hip_runtime.h>

// MedianFilter1D: x[16,64,16384] fp32, k=9, zero-pad 4 each side, lower median
// (= true median for odd k). Memory-bound: 128 MiB traffic -> ~20us floor.

#define L_ROW  16384
#define L_MASK 16383

__device__ __forceinline__ void s2(float &a, float &b) {
    float lo = fminf(a, b);
    float hi = fmaxf(a, b);
    a = lo; b = hi;
}

// Paeth's 19-CE median-of-9 network; returns the element at sorted pos 4.
__device__ __forceinline__ float med9(float p0, float p1, float p2, float p3,
                                      float p4, float p5, float p6, float p7,
                                      float p8) {
    s2(p1, p2); s2(p4, p5); s2(p7, p8);
    s2(p0, p1); s2(p3, p4); s2(p6, p7);
    s2(p1, p2); s2(p4, p5); s2(p7, p8);
    s2(p0, p3); s2(p5, p8); s2(p4, p7);
    s2(p3, p6); s2(p1, p4); s2(p2, p5);
    s2(p4, p7); s2(p4, p2); s2(p6, p4);
    s2(p4, p2);
    return p4;
}

__global__ __launch_bounds__(256, 4)
void MedianFilter1D_66924180406949_kernel(const float* __restrict__ x,
                                          float* __restrict__ y) {
    const int vec = blockIdx.x * 256 + threadIdx.x;   // float4 index
    const int pos = vec << 2;                         // element index (flat)
    const int inrow = pos & L_MASK;                   // position within row

    const float4* __restrict__ xv = (const float4*)x;

    float4 B = xv[vec];
    float4 A, C;
    if (inrow == 0) {                 // left row edge: zero pad
        A = make_float4(0.f, 0.f, 0.f, 0.f);
    } else {
        A = xv[vec - 1];
    }
    if (inrow == (L_ROW - 4)) {       // right row edge: zero pad
        C = make_float4(0.f, 0.f, 0.f, 0.f);
    } else {
        C = xv[vec + 1];
    }

    // 12-wide window A.x..C.w covers the 4 outputs' 9-element windows.
    float4 o;
    o.x = med9(A.x, A.y, A.z, A.w, B.x, B.y, B.z, B.w, C.x);
    o.y = med9(A.y, A.z, A.w, B.x, B.y, B.z, B.w, C.x, C.y);
    o.z = med9(A.z, A.w, B.x, B.y, B.z, B.w, C.x, C.y, C.z);
    o.w = med9(A.w, B.x, B.y, B.z, B.w, C.x, C.y, C.z, C.w);

    ((float4*)y)[vec] = o;
}

extern "C" void kernel_launch(void* const* d_in, const int* in_sizes, int n_in,
                              void* d_out, int out_size, void* d_ws, size_t ws_size,
                              hipStream_t stream) {
    const float* x = (const float*)d_in[0];
    float* y = (float*)d_out;
    const int total = in_sizes[0];          // 16 * 64 * 16384 = 16777216
    const int threads = total / 4;          // one float4 per thread
    const int blocks = threads / 256;       // 16384 blocks
    MedianFilter1D_66924180406949_kernel<<<blocks, 256, 0, stream>>>(x, y);
}

// Round 3
// 108.466 us; speedup vs baseline: 1.0191x; 1.0191x over previous
//
#include <hip/hip_runtime.h>

// MedianFilter1D: x[16,64,16384] fp32, k=9, zero-pad 4 each side, lower median.
// Memory-bound: 128 MiB compulsory HBM traffic -> ~20us kernel floor.
// R3: same as R2 (8 outputs/thread, 4 aligned 16B loads, nontemporal store)
// but with clang native vector type so __builtin_nontemporal_store compiles.

#define L_ROW  16384
#define L_MASK 16383

typedef float v4f __attribute__((ext_vector_type(4)));

__device__ __forceinline__ void s2(float &a, float &b) {
    float lo = fminf(a, b);
    float hi = fmaxf(a, b);
    a = lo; b = hi;
}

// Paeth's 19-CE median-of-9 network; returns the element at sorted pos 4.
__device__ __forceinline__ float med9(float p0, float p1, float p2, float p3,
                                      float p4, float p5, float p6, float p7,
                                      float p8) {
    s2(p1, p2); s2(p4, p5); s2(p7, p8);
    s2(p0, p1); s2(p3, p4); s2(p6, p7);
    s2(p1, p2); s2(p4, p5); s2(p7, p8);
    s2(p0, p3); s2(p5, p8); s2(p4, p7);
    s2(p3, p6); s2(p1, p4); s2(p2, p5);
    s2(p4, p7); s2(p4, p2); s2(p6, p4);
    s2(p4, p2);
    return p4;
}

__global__ __launch_bounds__(256, 4)
void MedianFilter1D_66924180406949_kernel(const float* __restrict__ x,
                                          float* __restrict__ y) {
    const int tid = blockIdx.x * 256 + threadIdx.x;   // 8-element group index
    const int v   = tid << 1;                         // base float4 index
    const int pos = tid << 3;                         // element index (flat)
    const int inrow = pos & L_MASK;                   // position within row

    const v4f* __restrict__ xv = (const v4f*)x;

    // Window w[0..15] = elements [pos-4 .. pos+11]
    v4f A, B0, B1, C;
    B0 = xv[v];
    B1 = xv[v + 1];
    if (inrow == 0) {                    // left row edge: zero pad
        A = (v4f){0.f, 0.f, 0.f, 0.f};
    } else {
        A = xv[v - 1];
    }
    if (inrow == (L_ROW - 8)) {          // right row edge: zero pad
        C = (v4f){0.f, 0.f, 0.f, 0.f};
    } else {
        C = xv[v + 2];
    }

    const float w0 = A.x,  w1 = A.y,  w2 = A.z,  w3 = A.w;
    const float w4 = B0.x, w5 = B0.y, w6 = B0.z, w7 = B0.w;
    const float w8 = B1.x, w9 = B1.y, w10 = B1.z, w11 = B1.w;
    const float w12 = C.x, w13 = C.y, w14 = C.z, w15 = C.w;

    v4f o0, o1;
    o0.x = med9(w0, w1, w2,  w3,  w4,  w5,  w6,  w7,  w8);
    o0.y = med9(w1, w2, w3,  w4,  w5,  w6,  w7,  w8,  w9);
    o0.z = med9(w2, w3, w4,  w5,  w6,  w7,  w8,  w9,  w10);
    o0.w = med9(w3, w4, w5,  w6,  w7,  w8,  w9,  w10, w11);
    o1.x = med9(w4, w5, w6,  w7,  w8,  w9,  w10, w11, w12);
    o1.y = med9(w5, w6, w7,  w8,  w9,  w10, w11, w12, w13);
    o1.z = med9(w6, w7, w8,  w9,  w10, w11, w12, w13, w14);
    o1.w = med9(w7, w8, w9,  w10, w11, w12, w13, w14, w15);

    v4f* __restrict__ yv = (v4f*)y;
    __builtin_nontemporal_store(o0, &yv[v]);
    __builtin_nontemporal_store(o1, &yv[v + 1]);
}

extern "C" void kernel_launch(void* const* d_in, const int* in_sizes, int n_in,
                              void* d_out, int out_size, void* d_ws, size_t ws_size,
                              hipStream_t stream) {
    const float* x = (const float*)d_in[0];
    float* y = (float*)d_out;
    const int total = in_sizes[0];          // 16 * 64 * 16384 = 16777216
    const int threads = total / 8;          // one 8-element group per thread
    const int blocks = threads / 256;       // 8192 blocks
    MedianFilter1D_66924180406949_kernel<<<blocks, 256, 0, stream>>>(x, y);
}